// Round 1
// baseline (274.972 us; speedup 1.0000x reference)
//
#include <hip/hip_runtime.h>
#include <math.h>

// excess[b,m] = K·T + SIGMA*e*(T^4 - Tenv^4) - (H+F);  out = mean(|excess|)
// K = 5-band stencil on a 13x13 grid; GLx = -K[1][2]; GR = e_diag[1];
// interface rows {0,12,156,168} are identity rows with e=0.
//
// v5: one thread = one grid ROW (13 contiguous floats).  e = 13*r + i, so
// the i-conditionals (east/west/interface) are compile-time in a fully
// unrolled loop; north/south rows are rows r+-1, loaded directly (they are
// the same cache lines adjacent lanes load as their own rows -> L1 hits).
// No shuffles, no fringe divergence, no batch-crossing Tenv logic.
// Out-of-batch neighbors: address clamped to own row (always in-bounds),
// value zeroed via fN/fS fmaf multipliers.

#define SIGMA_F 5.67e-8f

constexpr int BLOCK = 256;

typedef float f4a __attribute__((ext_vector_type(4), aligned(4)));  // 4B-aligned x4

__global__ __launch_bounds__(256) void fused_residual_v5(
    const float* __restrict__ T,      // [B*169]
    const float* __restrict__ H,
    const float* __restrict__ F,
    const float* __restrict__ Tenv,   // [B]
    const float* __restrict__ K,      // [169*169]
    const float* __restrict__ Ediag,  // [169]
    float* __restrict__ partials,
    int rows)                         // B*13
{
    __shared__ float sred[BLOCK / 64];

    const float GLx = -K[1 * 169 + 2];     // interior coupling (dx==dy -> GLx==GLy)
    const float GRs = SIGMA_F * Ediag[1];  // sigma * GR

    float acc = 0.0f;

    const int gstride = gridDim.x * BLOCK;
    for (int r = blockIdx.x * BLOCK + (int)threadIdx.x; r < rows; r += gstride) {
        const unsigned ur = (unsigned)r;
        const unsigned b  = ur / 13u;              // magic-mul
        const int j = (int)(ur - b * 13u);         // row within batch, 0..12
        const bool cS = (j > 0), cN = (j < 12);
        const float fS = cS ? 1.0f : 0.0f;
        const float fN = cN ? 1.0f : 0.0f;

        const int e0 = r * 13;
        const float* Tp = T + e0;
        const float* Sp = T + (cS ? e0 - 13 : e0); // clamped: always in-bounds
        const float* Np = T + (cN ? e0 + 13 : e0);

        // own row (13 floats), 4B-aligned vector loads
        f4a tA = *(const f4a*)(Tp);
        f4a tB = *(const f4a*)(Tp + 4);
        f4a tC = *(const f4a*)(Tp + 8);
        float t12 = Tp[12];
        // south row
        f4a sA = *(const f4a*)(Sp);
        f4a sB = *(const f4a*)(Sp + 4);
        f4a sC = *(const f4a*)(Sp + 8);
        float s12 = Sp[12];
        // north row
        f4a nA = *(const f4a*)(Np);
        f4a nB = *(const f4a*)(Np + 4);
        f4a nC = *(const f4a*)(Np + 8);
        float n12 = Np[12];
        // heat loads (single-use -> nontemporal)
        f4a hA = __builtin_nontemporal_load((const f4a*)(H + e0));
        f4a hB = __builtin_nontemporal_load((const f4a*)(H + e0 + 4));
        f4a hC = __builtin_nontemporal_load((const f4a*)(H + e0 + 8));
        float h12 = __builtin_nontemporal_load(H + e0 + 12);
        f4a fA = __builtin_nontemporal_load((const f4a*)(F + e0));
        f4a fB = __builtin_nontemporal_load((const f4a*)(F + e0 + 4));
        f4a fC = __builtin_nontemporal_load((const f4a*)(F + e0 + 8));
        float f12 = __builtin_nontemporal_load(F + e0 + 12);

        const float tv  = Tenv[b];
        const float tv2 = tv * tv;
        const float nGtv4 = -(GRs * (tv2 * tv2));  // -GRs*Tenv^4

        const float tR[13] = {tA.x, tA.y, tA.z, tA.w, tB.x, tB.y, tB.z, tB.w,
                              tC.x, tC.y, tC.z, tC.w, t12};
        const float sR[13] = {sA.x, sA.y, sA.z, sA.w, sB.x, sB.y, sB.z, sB.w,
                              sC.x, sC.y, sC.z, sC.w, s12};
        const float nR[13] = {nA.x, nA.y, nA.z, nA.w, nB.x, nB.y, nB.z, nB.w,
                              nC.x, nC.y, nC.z, nC.w, n12};
        const float qR[13] = {hA.x + fA.x, hA.y + fA.y, hA.z + fA.z, hA.w + fA.w,
                              hB.x + fB.x, hB.y + fB.y, hB.z + fB.z, hB.w + fB.w,
                              hC.x + fC.x, hC.y + fC.y, hC.z + fC.z, hC.w + fC.w,
                              h12 + f12};

        const float nnI = 2.0f + fN + fS;   // interior i: E and W both present
        const float nnE = 1.0f + fN + fS;   // i==0 / i==12: one of E/W missing
        const bool ifc = (j == 0) | (j == 12);  // with i in {0,12}: interface node

        // i == 0 (west edge; interface when j in {0,12})
        {
            float t = tR[0];
            float s = tR[1];
            s = fmaf(fN, nR[0], s);
            s = fmaf(fS, sR[0], s);
            float t2 = t * t;
            float ex = fmaf(GLx, fmaf(nnE, t, -s), fmaf(GRs, t2 * t2, nGtv4)) - qR[0];
            float exI = t - qR[0];
            acc += fabsf(ifc ? exI : ex);
        }
        // i == 1..11: fully interior in x, branch-free
        #pragma unroll
        for (int i = 1; i < 12; ++i) {
            float t = tR[i];
            float s = tR[i - 1] + tR[i + 1];
            s = fmaf(fN, nR[i], s);
            s = fmaf(fS, sR[i], s);
            float t2 = t * t;
            float ex = fmaf(GLx, fmaf(nnI, t, -s), fmaf(GRs, t2 * t2, nGtv4)) - qR[i];
            acc += fabsf(ex);
        }
        // i == 12 (east edge; interface when j in {0,12})
        {
            float t = tR[12];
            float s = tR[11];
            s = fmaf(fN, nR[12], s);
            s = fmaf(fS, sR[12], s);
            float t2 = t * t;
            float ex = fmaf(GLx, fmaf(nnE, t, -s), fmaf(GRs, t2 * t2, nGtv4)) - qR[12];
            float exI = t - qR[12];
            acc += fabsf(ifc ? exI : ex);
        }
    }

    #pragma unroll
    for (int off = 32; off > 0; off >>= 1)
        acc += __shfl_down(acc, off, 64);
    const int lane = threadIdx.x & 63;
    const int wid  = threadIdx.x >> 6;
    if (lane == 0) sred[wid] = acc;
    __syncthreads();
    if (threadIdx.x == 0) {
        float s = 0.0f;
        #pragma unroll
        for (int w = 0; w < BLOCK / 64; ++w) s += sred[w];
        partials[blockIdx.x] = s;
    }
}

__global__ __launch_bounds__(256) void finalize_kernel(
    const float* __restrict__ partials, int n,
    float* __restrict__ out, float inv_total)
{
    __shared__ float sred[BLOCK / 64];
    float acc = 0.0f;
    for (int i = (int)threadIdx.x; i < n; i += BLOCK) acc += partials[i];
    #pragma unroll
    for (int off = 32; off > 0; off >>= 1)
        acc += __shfl_down(acc, off, 64);
    int lane = threadIdx.x & 63;
    int wid  = threadIdx.x >> 6;
    if (lane == 0) sred[wid] = acc;
    __syncthreads();
    if (threadIdx.x == 0) {
        float s = 0.0f;
        #pragma unroll
        for (int w = 0; w < BLOCK / 64; ++w) s += sred[w];
        out[0] = s * inv_total;
    }
}

extern "C" void kernel_launch(void* const* d_in, const int* in_sizes, int n_in,
                              void* d_out, int out_size, void* d_ws, size_t ws_size,
                              hipStream_t stream) {
    const float* T    = (const float*)d_in[0];
    const float* H    = (const float*)d_in[1];
    const float* F    = (const float*)d_in[2];
    const float* Tenv = (const float*)d_in[3];
    const float* K    = (const float*)d_in[4];
    const float* E    = (const float*)d_in[5];
    float* out      = (float*)d_out;
    float* partials = (float*)d_ws;

    const int total = in_sizes[0];                 // B * 169 elements
    const int rows  = total / 13;                  // B * 13 rows

    // One row per thread, one-shot grid (6656 blocks for B=131072).
    int grid = (rows + BLOCK - 1) / BLOCK;
    if ((size_t)grid * sizeof(float) > ws_size) grid = (int)(ws_size / sizeof(float));
    if (grid < 1) grid = 1;

    fused_residual_v5<<<grid, BLOCK, 0, stream>>>(T, H, F, Tenv, K, E, partials, rows);

    const float inv_total = 1.0f / (float)total;
    finalize_kernel<<<1, BLOCK, 0, stream>>>(partials, grid, out, inv_total);
}

// Round 2
// 258.739 us; speedup vs baseline: 1.0627x; 1.0627x over previous
//
#include <hip/hip_runtime.h>
#include <math.h>

// excess[b,m] = K·T + SIGMA*e*(T^4 - Tenv^4) - (H+F);  out = mean(|excess|)
// K = 5-band stencil on a 13x13 grid; GLx = -K[1][2]; GR = e_diag[1];
// interface nodes {0,12,156,168} are identity rows with e=0.
//
// v6 = v4's memory pattern + v5's math.
//  - STAGE: block loads its tile LINEARLY into LDS with 16B-aligned dwordx4
//    streams (T window incl. +-16-float halo; Q = H+F combined at stage time).
//    This is the exact coalesced pattern that ran at 2.16 TB/s in v4.
//  - COMPUTE: one thread = one 13-float row, read from LDS. Row stride 13 is
//    coprime with 32 banks -> conflict-free (2 lanes/bank over wave64 = free).
//    East/west/interface conditionals are compile-time via full unroll;
//    north/south are two fma-mask flags. ~9 VALU/element, branch-free.

#define SIGMA_F 5.67e-8f

constexpr int BLOCK = 256;
constexpr int TWIN  = 3360;   // 16 front halo + 256*13 + 16 back halo (floats)
constexpr int QWIN  = 3328;   // 256*13

typedef float f4 __attribute__((ext_vector_type(4), aligned(16)));

__global__ __launch_bounds__(256) void fused_residual_v6(
    const float* __restrict__ T,      // [B*169]
    const float* __restrict__ H,
    const float* __restrict__ F,
    const float* __restrict__ Tenv,   // [B]
    const float* __restrict__ K,      // [169*169]
    const float* __restrict__ Ediag,  // [169]
    float* __restrict__ partials,
    int rows,                         // B*13
    int total)                        // B*169
{
    __shared__ float sT[TWIN];
    __shared__ float sQ[QWIN];
    __shared__ float sred[BLOCK / 64];

    const float GLx = -K[1 * 169 + 2];     // interior coupling (dx==dy -> GLx==GLy)
    const float GRs = SIGMA_F * Ediag[1];  // sigma * GR
    const int tid = (int)threadIdx.x;

    float acc = 0.0f;

    for (int blk = (int)blockIdx.x; blk * BLOCK < rows; blk += (int)gridDim.x) {
        const int r0 = blk * BLOCK;
        const int e0 = r0 * 13;           // 3328*blk -> *4B is 16B-aligned
        const int ws = e0 - 16;           // staged T window start (16B-aligned)

        if (blk != (int)blockIdx.x) __syncthreads();  // protect LDS reuse

        const bool fast = (ws >= 0) && (ws + TWIN <= total);
        if (fast) {
            #pragma unroll
            for (int it = 0; it < 4; ++it) {
                const int idx = tid + it * BLOCK;          // vec4 index
                if (idx < TWIN / 4) {
                    f4 v = *(const f4*)(T + ws + idx * 4);
                    *(f4*)(sT + idx * 4) = v;
                }
                if (idx < QWIN / 4) {
                    f4 h = __builtin_nontemporal_load((const f4*)(H + e0 + idx * 4));
                    f4 f = __builtin_nontemporal_load((const f4*)(F + e0 + idx * 4));
                    *(f4*)(sQ + idx * 4) = h + f;
                }
            }
        } else {
            // first/last block only: scalar, clamped, exact
            for (int k = tid; k < TWIN; k += BLOCK) {
                int g = ws + k;
                g = g < 0 ? 0 : (g >= total ? total - 1 : g);
                sT[k] = T[g];              // halo beyond array: clamped (finite);
            }                              // masked by fN/fS=0 in compute
            for (int k = tid; k < QWIN; k += BLOCK) {
                int g = e0 + k;
                sQ[k] = (g < total) ? (H[g] + F[g]) : 0.0f;
            }
        }
        __syncthreads();

        const int r = r0 + tid;
        if (r < rows) {
            const unsigned b = (unsigned)r / 13u;     // magic-mul
            const int j = r - (int)(b * 13u);         // grid row 0..12
            const float fS = (j > 0)  ? 1.0f : 0.0f;
            const float fN = (j < 12) ? 1.0f : 0.0f;
            const bool ifc = (j == 0) | (j == 12);    // with i in {0,12}

            const float tv  = Tenv[b];
            const float tv2 = tv * tv;
            const float nGtv4 = -(GRs * (tv2 * tv2)); // -GRs*Tenv^4

            const int lb = 16 + tid * 13;             // own row base in sT

            float tR[13], sv[13], nv[13], qv[13];
            #pragma unroll
            for (int i = 0; i < 13; ++i) tR[i] = sT[lb + i];
            #pragma unroll
            for (int i = 0; i < 13; ++i) sv[i] = sT[lb - 13 + i];
            #pragma unroll
            for (int i = 0; i < 13; ++i) nv[i] = sT[lb + 13 + i];
            #pragma unroll
            for (int i = 0; i < 13; ++i) qv[i] = sQ[tid * 13 + i];

            const float nnI = 2.0f + fN + fS;  // interior i
            const float nnE = 1.0f + fN + fS;  // i==0 / i==12

            // i == 0 (west edge; interface when j in {0,12})
            {
                float t = tR[0];
                float s = tR[1];
                s = fmaf(fN, nv[0], s);
                s = fmaf(fS, sv[0], s);
                float t2 = t * t;
                float ex = fmaf(GLx, fmaf(nnE, t, -s), fmaf(GRs, t2 * t2, nGtv4)) - qv[0];
                acc += fabsf(ifc ? (t - qv[0]) : ex);
            }
            // i == 1..11: fully interior in x, branch-free
            #pragma unroll
            for (int i = 1; i < 12; ++i) {
                float t = tR[i];
                float s = tR[i - 1] + tR[i + 1];
                s = fmaf(fN, nv[i], s);
                s = fmaf(fS, sv[i], s);
                float t2 = t * t;
                acc += fabsf(fmaf(GLx, fmaf(nnI, t, -s), fmaf(GRs, t2 * t2, nGtv4)) - qv[i]);
            }
            // i == 12 (east edge; interface when j in {0,12})
            {
                float t = tR[12];
                float s = tR[11];
                s = fmaf(fN, nv[12], s);
                s = fmaf(fS, sv[12], s);
                float t2 = t * t;
                float ex = fmaf(GLx, fmaf(nnE, t, -s), fmaf(GRs, t2 * t2, nGtv4)) - qv[12];
                acc += fabsf(ifc ? (t - qv[12]) : ex);
            }
        }
    }

    #pragma unroll
    for (int off = 32; off > 0; off >>= 1)
        acc += __shfl_down(acc, off, 64);
    const int lane = tid & 63;
    const int wid  = tid >> 6;
    if (lane == 0) sred[wid] = acc;
    __syncthreads();
    if (tid == 0) {
        float s = 0.0f;
        #pragma unroll
        for (int w = 0; w < BLOCK / 64; ++w) s += sred[w];
        partials[blockIdx.x] = s;
    }
}

__global__ __launch_bounds__(256) void finalize_kernel(
    const float* __restrict__ partials, int n,
    float* __restrict__ out, float inv_total)
{
    __shared__ float sred[BLOCK / 64];
    float acc = 0.0f;
    for (int i = (int)threadIdx.x; i < n; i += BLOCK) acc += partials[i];
    #pragma unroll
    for (int off = 32; off > 0; off >>= 1)
        acc += __shfl_down(acc, off, 64);
    int lane = threadIdx.x & 63;
    int wid  = threadIdx.x >> 6;
    if (lane == 0) sred[wid] = acc;
    __syncthreads();
    if (threadIdx.x == 0) {
        float s = 0.0f;
        #pragma unroll
        for (int w = 0; w < BLOCK / 64; ++w) s += sred[w];
        out[0] = s * inv_total;
    }
}

extern "C" void kernel_launch(void* const* d_in, const int* in_sizes, int n_in,
                              void* d_out, int out_size, void* d_ws, size_t ws_size,
                              hipStream_t stream) {
    const float* T    = (const float*)d_in[0];
    const float* H    = (const float*)d_in[1];
    const float* F    = (const float*)d_in[2];
    const float* Tenv = (const float*)d_in[3];
    const float* K    = (const float*)d_in[4];
    const float* E    = (const float*)d_in[5];
    float* out      = (float*)d_out;
    float* partials = (float*)d_ws;

    const int total = in_sizes[0];                 // B * 169
    const int rows  = total / 13;                  // B * 13

    // One block per 256 rows; one-shot grid (6656 for B=131072).
    int grid = (rows + BLOCK - 1) / BLOCK;
    if ((size_t)grid * sizeof(float) > ws_size) grid = (int)(ws_size / sizeof(float));
    if (grid < 1) grid = 1;

    fused_residual_v6<<<grid, BLOCK, 0, stream>>>(T, H, F, Tenv, K, E, partials,
                                                  rows, total);

    const float inv_total = 1.0f / (float)total;
    finalize_kernel<<<1, BLOCK, 0, stream>>>(partials, grid, out, inv_total);
}

// Round 3
// 244.837 us; speedup vs baseline: 1.1231x; 1.0568x over previous
//
#include <hip/hip_runtime.h>
#include <math.h>

// excess[b,m] = K·T + SIGMA*e*(T^4 - Tenv^4) - (H+F);  out = mean(|excess|)
// K = 5-band stencil on a 13x13 grid; GLx = -K[1][2]; GR = e_diag[1];
// interface nodes {0,12,156,168} are identity rows with e=0.
//
// v7 = v4's exact memory structure (one-shot grid, 8 elems/thread, 6 coalesced
// dwordx4 loads, shuffle neighbors + fringe patches, no compute barrier)
// with the per-element VALU hog replaced by a 176-entry LDS mask table:
//  - tab[m] packs the 4 geometric neighbor masks as bytes -> v_cvt_f32_ubyte
//  - masked neighbor sum = 4 fma (replaces cmp/cndmask chains)
//  - interface test: nn == 2 (the 4 interface nodes are exactly the grid
//    corners, the only nodes with 2 geometric neighbors) -> exact select
//  - table padded to 176 (wrap replicated) -> index m0+j, no mod, and the
//    serial m/ii/wrap dependency chain of v4 is gone (8 indep elements).

#define SIGMA_F 5.67e-8f

constexpr int BLOCK = 256;

typedef float f4a __attribute__((ext_vector_type(4), aligned(4)));   // unaligned x4
typedef float f4b __attribute__((ext_vector_type(4), aligned(16)));  // aligned x4

__global__ __launch_bounds__(256) void fused_residual_v7(
    const float* __restrict__ T,      // [B*169]
    const float* __restrict__ H,
    const float* __restrict__ F,
    const float* __restrict__ Tenv,   // [B]
    const float* __restrict__ K,      // [169*169]
    const float* __restrict__ Ediag,  // [169]
    float* __restrict__ partials,
    int total)
{
    __shared__ unsigned sTab[176];
    __shared__ float sred[BLOCK / 64];

    const float GLx = -K[1 * 169 + 2];     // interior coupling (dx==dy -> GLx==GLy)
    const float GRs = SIGMA_F * Ediag[1];  // sigma * GR

    const int tid  = (int)threadIdx.x;
    const int lane = tid & 63;

    // ---- build the per-m mask table (704 B, once per block) ----
    if (tid < 176) {
        int m = (tid < 169) ? tid : tid - 169;   // pad: wrap replicated
        int ii = m % 13;
        unsigned cW = (ii > 0)   ? 1u : 0u;
        unsigned cE = (ii < 12)  ? 1u : 0u;
        unsigned cN = (m < 156)  ? 1u : 0u;
        unsigned cS = (m >= 13)  ? 1u : 0u;
        sTab[tid] = cW | (cE << 8) | (cN << 16) | (cS << 24);
    }
    __syncthreads();

    float acc = 0.0f;

    const int gstride = gridDim.x * BLOCK;
    for (int g = blockIdx.x * BLOCK + tid; g * 8 < total; g += gstride) {
        const int e0 = g * 8;
        const int waveBase = e0 - lane * 8;
        const bool fast = (waveBase >= 16) && (waveBase + 64 * 8 + 16 <= total);

        if (fast) {
            // 6 independent wide loads, issued before any use
            f4b t0 = *(const f4b*)(T + e0);
            f4b t1 = *(const f4b*)(T + e0 + 4);
            f4b h0 = __builtin_nontemporal_load((const f4b*)(H + e0));
            f4b h1 = __builtin_nontemporal_load((const f4b*)(H + e0 + 4));
            f4b f0 = __builtin_nontemporal_load((const f4b*)(F + e0));
            f4b f1 = __builtin_nontemporal_load((const f4b*)(F + e0 + 4));

            // South: value at local idx 8*lane + j - 13
            float sv[8];
            sv[0] = __shfl_up(t0.w, 2);
            sv[1] = __shfl_up(t1.x, 2);
            sv[2] = __shfl_up(t1.y, 2);
            sv[3] = __shfl_up(t1.z, 2);
            sv[4] = __shfl_up(t1.w, 2);
            sv[5] = __shfl_up(t0.x, 1);
            sv[6] = __shfl_up(t0.y, 1);
            sv[7] = __shfl_up(t0.z, 1);
            if (lane < 2) {                       // fringe below wave window
                f4a a = *(const f4a*)(T + e0 - 13);
                f4a b = *(const f4a*)(T + e0 - 9);
                sv[0] = a.x; sv[1] = a.y; sv[2] = a.z; sv[3] = a.w;
                sv[4] = b.x; sv[5] = b.y; sv[6] = b.z; sv[7] = b.w;
            }
            // North: value at local idx 8*lane + j + 13
            float nv[8];
            nv[0] = __shfl_down(t1.y, 1);
            nv[1] = __shfl_down(t1.z, 1);
            nv[2] = __shfl_down(t1.w, 1);
            nv[3] = __shfl_down(t0.x, 2);
            nv[4] = __shfl_down(t0.y, 2);
            nv[5] = __shfl_down(t0.z, 2);
            nv[6] = __shfl_down(t0.w, 2);
            nv[7] = __shfl_down(t1.x, 2);
            if (lane >= 62) {                     // fringe above wave window
                f4a a = *(const f4a*)(T + e0 + 13);
                f4a b = *(const f4a*)(T + e0 + 17);
                nv[0] = a.x; nv[1] = a.y; nv[2] = a.z; nv[3] = a.w;
                nv[4] = b.x; nv[5] = b.y; nv[6] = b.z; nv[7] = b.w;
            }
            // West / East chunk edges
            float left = __shfl_up(t1.w, 1);
            if (lane == 0) left = T[e0 - 1];
            float right = __shfl_down(t0.x, 1);
            if (lane == 63) right = T[e0 + 8];

            const unsigned ue = (unsigned)e0;
            const unsigned b0 = ue / 169u;        // magic-mul
            const int m0 = (int)(ue - b0 * 169u);

            float tvA = Tenv[b0];
            float tvB = tvA;
            if (m0 >= 162) tvB = Tenv[b0 + 1];    // 8-group crosses batch boundary
            const float tv4A = (tvA * tvA) * (tvA * tvA);
            const float tv4B = (tvB * tvB) * (tvB * tvB);

            const float tCv[8] = {t0.x, t0.y, t0.z, t0.w, t1.x, t1.y, t1.z, t1.w};
            const float tWv[8] = {left, t0.x, t0.y, t0.z, t0.w, t1.x, t1.y, t1.z};
            const float tEv[8] = {t0.y, t0.z, t0.w, t1.x, t1.y, t1.z, t1.w, right};
            const float hq[8]  = {h0.x + f0.x, h0.y + f0.y, h0.z + f0.z, h0.w + f0.w,
                                  h1.x + f1.x, h1.y + f1.y, h1.z + f1.z, h1.w + f1.w};

            #pragma unroll
            for (int j = 0; j < 8; ++j) {
                const unsigned w = sTab[m0 + j];            // padded: no mod
                const float mW = (float)(w & 0xffu);        // v_cvt_f32_ubyte0
                const float mE = (float)((w >> 8) & 0xffu);
                const float mN = (float)((w >> 16) & 0xffu);
                const float mS = (float)(w >> 24);

                const float t = tCv[j];
                float s = mW * tWv[j];
                s = fmaf(mE, tEv[j], s);
                s = fmaf(mN, nv[j], s);
                s = fmaf(mS, sv[j], s);
                const float nn = (mW + mE) + (mN + mS);
                const float q  = hq[j];
                const float tv4 = (m0 + j >= 169) ? tv4B : tv4A;
                const float t2 = t * t;
                const float d  = fmaf(t2, t2, -tv4);        // t^4 - tv^4
                const float core = fmaf(GLx, fmaf(nn, t, -s), fmaf(GRs, d, -q));
                const float ex = (nn == 2.0f) ? (t - q) : core;  // interface = corner
                acc += fabsf(ex);
            }
        } else {
            // boundary waves (first/last of the grid): scalar, exact, in-bounds
            #pragma unroll
            for (int j = 0; j < 8; ++j) {
                int e = e0 + j;
                if (e >= total) break;
                unsigned b = (unsigned)e / 169u;
                int m = e - (int)b * 169;
                unsigned q13 = (unsigned)m / 13u;
                int ii = m - (int)q13 * 13;
                bool cE = (ii < 12), cW = (ii > 0), cN = (m < 156), cS = (m >= 13);
                bool ifc = (m == 0) | (m == 12) | (m == 156) | (m == 168);
                float t  = T[e];
                float tEv2 = cE ? T[e + 1]  : 0.0f;
                float tWv2 = cW ? T[e - 1]  : 0.0f;
                float tNv2 = cN ? T[e + 13] : 0.0f;
                float tSv2 = cS ? T[e - 13] : 0.0f;
                float s  = tEv2 + tWv2 + tNv2 + tSv2;
                float nn = (float)((int)cE + (int)cW + (int)cN + (int)cS);
                float tv = Tenv[b];
                float tv4 = (tv * tv) * (tv * tv);
                float t2 = t * t, t4 = t2 * t2;
                float qq = H[e] + F[e];
                float ex = ifc ? (t - qq)
                               : (GLx * (nn * t - s) + GRs * (t4 - tv4) - qq);
                acc += fabsf(ex);
            }
        }
    }

    #pragma unroll
    for (int off = 32; off > 0; off >>= 1)
        acc += __shfl_down(acc, off, 64);
    const int wid = tid >> 6;
    if (lane == 0) sred[wid] = acc;
    __syncthreads();
    if (tid == 0) {
        float s = 0.0f;
        #pragma unroll
        for (int w = 0; w < BLOCK / 64; ++w) s += sred[w];
        partials[blockIdx.x] = s;
    }
}

__global__ __launch_bounds__(256) void finalize_kernel(
    const float* __restrict__ partials, int n,
    float* __restrict__ out, float inv_total)
{
    __shared__ float sred[BLOCK / 64];
    float acc = 0.0f;
    for (int i = (int)threadIdx.x; i < n; i += BLOCK) acc += partials[i];
    #pragma unroll
    for (int off = 32; off > 0; off >>= 1)
        acc += __shfl_down(acc, off, 64);
    int lane = threadIdx.x & 63;
    int wid  = threadIdx.x >> 6;
    if (lane == 0) sred[wid] = acc;
    __syncthreads();
    if (threadIdx.x == 0) {
        float s = 0.0f;
        #pragma unroll
        for (int w = 0; w < BLOCK / 64; ++w) s += sred[w];
        out[0] = s * inv_total;
    }
}

extern "C" void kernel_launch(void* const* d_in, const int* in_sizes, int n_in,
                              void* d_out, int out_size, void* d_ws, size_t ws_size,
                              hipStream_t stream) {
    const float* T    = (const float*)d_in[0];
    const float* H    = (const float*)d_in[1];
    const float* F    = (const float*)d_in[2];
    const float* Tenv = (const float*)d_in[3];
    const float* K    = (const float*)d_in[4];
    const float* E    = (const float*)d_in[5];
    float* out      = (float*)d_out;
    float* partials = (float*)d_ws;

    const int total = in_sizes[0];                      // 131072 * 169

    // One-shot grid: every thread runs its loop body exactly once.
    int grid = (total / 8 + BLOCK - 1) / BLOCK;         // 10816 for B=131072
    if ((size_t)grid * sizeof(float) > ws_size) grid = (int)(ws_size / sizeof(float));
    if (grid < 1) grid = 1;

    fused_residual_v7<<<grid, BLOCK, 0, stream>>>(T, H, F, Tenv, K, E, partials, total);

    const float inv_total = 1.0f / (float)total;
    finalize_kernel<<<1, BLOCK, 0, stream>>>(partials, grid, out, inv_total);
}